// Round 14
// baseline (260.075 us; speedup 1.0000x reference)
//
#include <hip/hip_runtime.h>

#define BB 2
#define S 2048
#define H 16
#define DH 64
#define DIM 1024
#define WIN 512

#define OUT_PK 0
#define OUT_QP 134217728
#define OUT_RQ 268435456
#define OUT_RK 268959744

// ws float offsets (PK-side c-vectors only)
#define WS_C0K   (1024 + 2*65536)
#define WS_C511K (1024 + 3*65536)
#define WS_BF_BASE 263168          // float index where bf16 region starts

typedef short bf16x8 __attribute__((ext_vector_type(8)));
typedef float f32x4 __attribute__((ext_vector_type(4)));

__device__ inline short f2bf(float f) {
    union { float f; unsigned int u; } cv; cv.f = f;
    unsigned int u = cv.u + 0x7FFFu + ((cv.u >> 16) & 1u);
    return (short)(u >> 16);
}

__device__ inline float bf2f(short s) {
    union { unsigned int u; float f; } cv;
    cv.u = ((unsigned int)(unsigned short)s) << 16;
    return cv.f;
}

// Launch 1: bid<256 -> fused LN+MFMA proj block; bid>=256 -> q/k f32->bf16 convert block.
__global__ __launch_bounds__(256) void prep1(const float* __restrict__ emb,
        const float* __restrict__ lnsc, const float* __restrict__ lnbi,
        const float* __restrict__ Wq, const float* __restrict__ bq,
        const float* __restrict__ Wk, const float* __restrict__ bk,
        const float* __restrict__ q, const float* __restrict__ k,
        float* __restrict__ out, short* __restrict__ rqbf, short* __restrict__ rkbf,
        short* __restrict__ qbf, short* __restrict__ kbf) {
    __shared__ short As[64 * 72];
    __shared__ short Bs[64 * 72];
    __shared__ float smu[64];
    __shared__ float srs[64];
    int bid = blockIdx.x;
    int t = threadIdx.x;

    if (bid >= 256) {
        int cb = bid - 256;            // 0..2047
        int z = cb >> 10;
        int blk = cb & 1023;
        const float* src = z ? k : q;
        short* dst = z ? kbf : qbf;
        int e0 = (blk * 256 + t) * 16;
        int c = e0 & 63, hh = (e0 >> 6) & 15, n = (e0 >> 10) & 2047, b = e0 >> 21;
        short* dbase = dst + (((size_t)(b * 16 + hh) * 2048) + n) * 64 + c;
#pragma unroll
        for (int i = 0; i < 4; ++i) {
            float4 v = *reinterpret_cast<const float4*>(src + e0 + i * 4);
            short4 o = { f2bf(v.x), f2bf(v.y), f2bf(v.z), f2bf(v.w) };
            *reinterpret_cast<short4*>(dbase + i * 4) = o;
        }
        return;
    }

    int z = bid >> 7;
    int d0i = ((bid >> 6) & 1) * 8 + (bid & 7);
    int r0i = (bid >> 3) & 7;
    const float* W    = z ? Wk : Wq;
    const float* bias = z ? bk : bq;
    float* o = out + (z ? OUT_RK : OUT_RQ);
    short* bfo = z ? rkbf : rqbf;
    int r0 = r0i * 64;
    int d0 = d0i * 64;

    {   // LN stats, 4 threads per row
        int rr = t >> 2, p = t & 3;
        const float4* rp = reinterpret_cast<const float4*>(emb + (r0 + rr) * DIM + p * 256);
        float s = 0.f, sq = 0.f;
#pragma unroll
        for (int i = 0; i < 64; ++i) {
            float4 v = rp[i];
            s  += v.x + v.y + v.z + v.w;
            sq += v.x * v.x + v.y * v.y + v.z * v.z + v.w * v.w;
        }
        s += __shfl_xor(s, 1); sq += __shfl_xor(sq, 1);
        s += __shfl_xor(s, 2); sq += __shfl_xor(sq, 2);
        if (p == 0) {
            float mu = s / DIM;
            float var = sq / DIM - mu * mu;
            smu[rr] = mu;
            srs[rr] = rsqrtf(var + 1e-5f);
        }
    }
    __syncthreads();

    int lane = t & 63, w = t >> 6, lr = lane & 15, lg = lane >> 4;
    int srow = t >> 2, seg = (t & 3) * 16;
    float mu = smu[srow], rs = srs[srow];

    f32x4 acc[4] = {};
    for (int c0 = 0; c0 < DIM; c0 += 64) {
        const float4* ep = reinterpret_cast<const float4*>(emb + (size_t)(r0 + srow) * DIM + c0 + seg);
        const float4* wp = reinterpret_cast<const float4*>(W + (size_t)(d0 + srow) * DIM + c0 + seg);
        short4* ad = reinterpret_cast<short4*>(&As[srow * 72 + seg]);
        short4* wd = reinterpret_cast<short4*>(&Bs[srow * 72 + seg]);
#pragma unroll
        for (int i = 0; i < 4; ++i) {
            float4 v = ep[i], wv = wp[i];
            int cb2 = c0 + seg + i * 4;
            float4 sc = *reinterpret_cast<const float4*>(lnsc + cb2);
            float4 bi = *reinterpret_cast<const float4*>(lnbi + cb2);
            short4 a4 = { f2bf((v.x - mu) * rs * sc.x + bi.x),
                          f2bf((v.y - mu) * rs * sc.y + bi.y),
                          f2bf((v.z - mu) * rs * sc.z + bi.z),
                          f2bf((v.w - mu) * rs * sc.w + bi.w) };
            short4 w4 = { f2bf(wv.x), f2bf(wv.y), f2bf(wv.z), f2bf(wv.w) };
            ad[i] = a4;
            wd[i] = w4;
        }
        __syncthreads();
#pragma unroll
        for (int kk = 0; kk < 2; ++kk) {
            bf16x8 a = *reinterpret_cast<const bf16x8*>(&As[(w * 16 + lr) * 72 + kk * 32 + lg * 8]);
#pragma unroll
            for (int cg = 0; cg < 4; ++cg) {
                bf16x8 b = *reinterpret_cast<const bf16x8*>(&Bs[(cg * 16 + lr) * 72 + kk * 32 + lg * 8]);
                acc[cg] = __builtin_amdgcn_mfma_f32_16x16x32_bf16(a, b, acc[cg], 0, 0, 0);
            }
        }
        __syncthreads();
    }
#pragma unroll
    for (int cg = 0; cg < 4; ++cg) {
        int col = d0 + cg * 16 + lr;
        float bv = bias[col];
        int hh = col >> 6, cc = col & 63;
#pragma unroll
        for (int reg = 0; reg < 4; ++reg) {
            int rr = r0 + w * 16 + lg * 4 + reg;
            float val = acc[cg][reg] + bv;
            o[(size_t)rr * DIM + col] = val;
            bfo[((size_t)(hh * 512) + rr) * 64 + cc] = f2bf(val);
        }
    }
}

// cvec_pk: c0k/c511k[j] = k[b,j,h] . rq[0/511,h]
__global__ __launch_bounds__(256) void cvec_pk(const short* __restrict__ kbf,
        const short* __restrict__ rqbf, float* __restrict__ ws) {
    int cid = blockIdx.x;           // 0..1023
    int bh = cid >> 5, rb = cid & 31;
    int t = threadIdx.x;
    int rr = t >> 2, p = t & 3;
    int n = rb * 64 + rr;
    int h = bh & 15;
    const short* X = kbf + ((size_t)bh * 2048 + n) * 64 + p * 16;
    const short* T = rqbf + (size_t)h * 512 * 64 + p * 16;
    bf16x8 x0 = *reinterpret_cast<const bf16x8*>(X);
    bf16x8 x1 = *reinterpret_cast<const bf16x8*>(X + 8);
    bf16x8 a0 = *reinterpret_cast<const bf16x8*>(T);
    bf16x8 a1 = *reinterpret_cast<const bf16x8*>(T + 8);
    bf16x8 c0 = *reinterpret_cast<const bf16x8*>(T + 511 * 64);
    bf16x8 c1 = *reinterpret_cast<const bf16x8*>(T + 511 * 64 + 8);
    float d0 = 0.f, d1 = 0.f;
#pragma unroll
    for (int e = 0; e < 8; ++e) {
        float xa = bf2f(x0[e]), xb = bf2f(x1[e]);
        d0 += xa * bf2f(a0[e]) + xb * bf2f(a1[e]);
        d1 += xa * bf2f(c0[e]) + xb * bf2f(c1[e]);
    }
    d0 += __shfl_xor(d0, 1); d0 += __shfl_xor(d0, 2);
    d1 += __shfl_xor(d1, 1); d1 += __shfl_xor(d1, 2);
    if (p == 0) {
        int o = bh * S + n;
        ws[WS_C0K + o] = d0; ws[WS_C511K + o] = d1;
    }
}

// qpk: QP side, one block per 64-row stripe. Compute Yt[64][512] = q-stripe . rk^T via MFMA,
// then emit full 8KB rows linearly: out[n][j] = Yt[n-n0][clamp(511+j-n)].
__global__ __launch_bounds__(256) void qpk(const short* __restrict__ qbf,
        const short* __restrict__ rkbf, float* __restrict__ out) {
    __shared__ short Yt[64 * 516];   // row stride 516 bf16 (1032 B): pad for aligned b64+4 reads

    int bid = blockIdx.x;
    int wid = (bid & 7) * 128 + (bid >> 3);   // 1024 = 8*128, bijective
    int bh = wid >> 5, nt = wid & 31;
    int h = bh & 15;
    int n0 = nt * 64;
    int t = threadIdx.x;
    int lane = t & 63, w = t >> 6, lr = lane & 15, lg = lane >> 4;

    // Same (lr,lg) lane convention for A and B as all prior rounds (k-permutation cancels).
    const short* arow = qbf + ((size_t)bh * 2048 + n0 + w * 16 + lr) * 64 + lg * 8;
    bf16x8 a0 = *reinterpret_cast<const bf16x8*>(arow);
    bf16x8 a1 = *reinterpret_cast<const bf16x8*>(arow + 32);
    const short* tb = rkbf + (size_t)h * 512 * 64 + lr * 64 + lg * 8;

    bf16x8 b0 = *reinterpret_cast<const bf16x8*>(tb);
    bf16x8 b1 = *reinterpret_cast<const bf16x8*>(tb + 32);
    for (int s = 0; s < 32; ++s) {
        bf16x8 nb0 = b0, nb1 = b1;
        if (s < 31) {
            const short* nb = tb + (s + 1) * 16 * 64;
            nb0 = *reinterpret_cast<const bf16x8*>(nb);
            nb1 = *reinterpret_cast<const bf16x8*>(nb + 32);
        }
        f32x4 acc = {0.f, 0.f, 0.f, 0.f};
        acc = __builtin_amdgcn_mfma_f32_16x16x32_bf16(a0, b0, acc, 0, 0, 0);
        acc = __builtin_amdgcn_mfma_f32_16x16x32_bf16(a1, b1, acc, 0, 0, 0);
        int g = s * 16 + lr;   // D col = lr -> B row s*16+lr; D row m = w*16+lg*4+reg
#pragma unroll
        for (int reg = 0; reg < 4; ++reg)
            Yt[(w * 16 + lg * 4 + reg) * 516 + g] = f2bf(acc[reg]);
        b0 = nb0; b1 = nb1;
    }
    __syncthreads();

    float* obase = out + OUT_QP + (size_t)bh * S * S;
    for (int i = 0; i < 16; ++i) {
        int m = w * 16 + i;
        int n = n0 + m;
        const short* yr = &Yt[m * 516];
        float v0 = bf2f(yr[0]), v511 = bf2f(yr[511]);
        int jA = n - 511;          // first j with rel >= 0
        int jB = n + 1;            // first j with rel > 511
        int dU = (511 - n) & 3;    // row-uniform misalignment (j0s, lane*4 are %4==0)
        for (int sg = 0; sg < 8; ++sg) {
            int j0s = sg * 256;
            int j = j0s + lane * 4;
            f32x4 v;
            if (j0s + 256 <= jA) {
                v = (f32x4){ v0, v0, v0, v0 };
            } else if (j0s >= jB) {
                v = (f32x4){ v511, v511, v511, v511 };
            } else if (j0s >= jA && j0s + 256 <= jB) {
                int ab = 511 + j - n - dU;     // %4 == 0, in [0, 508]
                short4 lo = *reinterpret_cast<const short4*>(yr + ab);
                short4 hi = *reinterpret_cast<const short4*>(yr + ab + 4);
                short e0, e1, e2, e3;
                if      (dU == 0) { e0 = lo.x; e1 = lo.y; e2 = lo.z; e3 = lo.w; }
                else if (dU == 1) { e0 = lo.y; e1 = lo.z; e2 = lo.w; e3 = hi.x; }
                else if (dU == 2) { e0 = lo.z; e1 = lo.w; e2 = hi.x; e3 = hi.y; }
                else              { e0 = lo.w; e1 = hi.x; e2 = hi.y; e3 = hi.z; }
                v = (f32x4){ bf2f(e0), bf2f(e1), bf2f(e2), bf2f(e3) };
            } else {
#pragma unroll
                for (int u = 0; u < 4; ++u) {
                    int rel = 511 + j + u - n;
                    rel = rel < 0 ? 0 : (rel > 511 ? 511 : rel);
                    v[u] = bf2f(yr[rel]);
                }
            }
            __builtin_nontemporal_store(v,
                reinterpret_cast<f32x4*>(obase + (size_t)n * S + j));
        }
    }
}

// pkk: PK side, R13-proven structure (nt-major sweep, 64x512 flat superblocks + band tiles).
// 373 blocks/panel, 32 panels = 11936 = 8*1492 (whole panels per XCD).
__global__ __launch_bounds__(256) void pkk(const short* __restrict__ kbf,
        const short* __restrict__ rqbf, const float* __restrict__ ws,
        float* __restrict__ out) {
    __shared__ short Yt[128 * 68];   // [g][m]

    int bid = blockIdx.x;
    int wid = (bid & 7) * 1492 + (bid >> 3);   // bijective
    int bh = wid / 373, o = wid % 373;
    int h = bh & 15;
    int t = threadIdx.x;
    float* obase = out + OUT_PK + (size_t)bh * S * S;

    int nt = 0, rem = o, nL = 0, nB = 0, jlo = 0;
    for (; nt < 32; ++nt) {
        jlo = nt > 8 ? nt - 8 : 0;
        nL = (jlo + 7) >> 3;
        nB = nt - jlo + 1;
        int nR = (38 - nt) >> 3;
        int tot = nL + nB + nR;
        if (rem < tot) break;
        rem -= tot;
    }
    int n0 = nt * 64;

    if (rem < nL || rem >= nL + nB) {
        int left, j0, W;
        if (rem < nL) { left = 1; j0 = rem * 512; W = jlo * 64 - j0; }
        else          { left = 0; int rr = rem - nL - nB; j0 = (nt + 1) * 64 + rr * 512; W = 2048 - j0; }
        if (W > 512) W = 512;
        const float* cv = ws + (left ? WS_C0K : WS_C511K) + bh * S;
        int w2 = t >> 7;
        int c = (t & 127) * 4;
        int active = c < W;
        f32x4 cvv = {0.f, 0.f, 0.f, 0.f};
        if (active) cvv = *reinterpret_cast<const f32x4*>(cv + j0 + c);
#pragma unroll
        for (int i = 0; i < 32; ++i) {
            int n = n0 + w2 * 32 + i;
            if (active)
                __builtin_nontemporal_store(cvv,
                    reinterpret_cast<f32x4*>(obase + (size_t)n * S + j0 + c));
        }
        return;
    }

    // band tile
    int jt = jlo + (rem - nL);
    int j0 = jt * 64;
    int rlo = 511 + j0 - (n0 + 63); rlo = rlo < 0 ? 0 : rlo;

    const short* xb = kbf + ((size_t)bh * 2048 + j0) * 64;
    const short* tbase = rqbf + (size_t)h * 512 * 64;

    int lane = t & 63, w = t >> 6, lr = lane & 15, lg = lane >> 4;
    const short* arow = xb + (w * 16 + lr) * 64 + lg * 8;
    bf16x8 a0 = *reinterpret_cast<const bf16x8*>(arow);
    bf16x8 a1 = *reinterpret_cast<const bf16x8*>(arow + 32);

    bf16x8 b0s[8], b1s[8];
#pragma unroll
    for (int s = 0; s < 8; ++s) {
        int trow = rlo + s * 16 + lr;
        trow = trow > 511 ? 511 : trow;
        const short* brow = tbase + trow * 64 + lg * 8;
        b0s[s] = *reinterpret_cast<const bf16x8*>(brow);
        b1s[s] = *reinterpret_cast<const bf16x8*>(brow + 32);
    }
#pragma unroll
    for (int s = 0; s < 8; ++s) {
        f32x4 acc = {0.f, 0.f, 0.f, 0.f};
        acc = __builtin_amdgcn_mfma_f32_16x16x32_bf16(a0, b0s[s], acc, 0, 0, 0);
        acc = __builtin_amdgcn_mfma_f32_16x16x32_bf16(a1, b1s[s], acc, 0, 0, 0);
        short4 pk4 = { f2bf(acc[0]), f2bf(acc[1]), f2bf(acc[2]), f2bf(acc[3]) };
        *reinterpret_cast<short4*>(&Yt[(s * 16 + lr) * 68 + w * 16 + lg * 4]) = pk4;
    }
    __syncthreads();

    int tx = t & 15, ty = t >> 4;
#pragma unroll
    for (int i = 0; i < 4; ++i) {
        int rowi = ty + i * 16;
        int n = n0 + rowi;
        float vv[4];
#pragma unroll
        for (int jj = 0; jj < 4; ++jj) {
            int j = j0 + tx * 4 + jj;
            int rel = 511 + j - n;
            rel = rel < 0 ? 0 : (rel > 511 ? 511 : rel);
            int g = rel - rlo;
            int m = tx * 4 + jj;
            vv[jj] = bf2f(Yt[g * 68 + m]);
        }
        f32x4 v = { vv[0], vv[1], vv[2], vv[3] };
        __builtin_nontemporal_store(v,
            reinterpret_cast<f32x4*>(obase + (size_t)n * S + j0 + tx * 4));
    }
}

extern "C" void kernel_launch(void* const* d_in, const int* in_sizes, int n_in,
                              void* d_out, int out_size, void* d_ws, size_t ws_size,
                              hipStream_t stream) {
    const float* q    = (const float*)d_in[0];
    const float* k    = (const float*)d_in[1];
    const float* emb  = (const float*)d_in[2];
    const float* lnsc = (const float*)d_in[3];
    const float* lnbi = (const float*)d_in[4];
    const float* Wq   = (const float*)d_in[5];
    const float* bq   = (const float*)d_in[6];
    const float* Wk   = (const float*)d_in[7];
    const float* bk   = (const float*)d_in[8];
    float* out = (float*)d_out;
    float* ws  = (float*)d_ws;

    short* qbf  = (short*)(ws + WS_BF_BASE);
    short* kbf  = qbf + (size_t)4194304;
    short* rqbf = kbf + (size_t)4194304;
    short* rkbf = rqbf + (size_t)524288;

    prep1<<<dim3(2304), dim3(256), 0, stream>>>(emb, lnsc, lnbi, Wq, bq, Wk, bk,
                                                q, k, out, rqbf, rkbf, qbf, kbf);
    cvec_pk<<<dim3(1024), dim3(256), 0, stream>>>(kbf, rqbf, ws);
    qpk<<<dim3(1024), dim3(256), 0, stream>>>(qbf, rkbf, out);
    pkk<<<dim3(11936), dim3(256), 0, stream>>>(kbf, rqbf, ws, out);
}

// Round 15
// 226.443 us; speedup vs baseline: 1.1485x; 1.1485x over previous
//
#include <hip/hip_runtime.h>

#define BB 2
#define S 2048
#define H 16
#define DH 64
#define DIM 1024
#define WIN 512

#define OUT_PK 0
#define OUT_QP 134217728
#define OUT_RQ 268435456
#define OUT_RK 268959744

// ws float offsets
#define WS_C0Q   1024
#define WS_C511Q (1024 + 65536)
#define WS_C0K   (1024 + 2*65536)
#define WS_C511K (1024 + 3*65536)
#define WS_BF_BASE 263168          // float index where bf16 region starts

typedef short bf16x8 __attribute__((ext_vector_type(8)));
typedef float f32x4 __attribute__((ext_vector_type(4)));

__device__ inline short f2bf(float f) {
    union { float f; unsigned int u; } cv; cv.f = f;
    unsigned int u = cv.u + 0x7FFFu + ((cv.u >> 16) & 1u);
    return (short)(u >> 16);
}

__device__ inline float bf2f(short s) {
    union { unsigned int u; float f; } cv;
    cv.u = ((unsigned int)(unsigned short)s) << 16;
    return cv.f;
}

// Launch 1: bid<256 -> fused LN+MFMA proj block; bid>=256 -> q/k f32->bf16 convert block.
__global__ __launch_bounds__(256) void prep1(const float* __restrict__ emb,
        const float* __restrict__ lnsc, const float* __restrict__ lnbi,
        const float* __restrict__ Wq, const float* __restrict__ bq,
        const float* __restrict__ Wk, const float* __restrict__ bk,
        const float* __restrict__ q, const float* __restrict__ k,
        float* __restrict__ out, short* __restrict__ rqbf, short* __restrict__ rkbf,
        short* __restrict__ qbf, short* __restrict__ kbf) {
    __shared__ short As[64 * 72];
    __shared__ short Bs[64 * 72];
    __shared__ float smu[64];
    __shared__ float srs[64];
    int bid = blockIdx.x;
    int t = threadIdx.x;

    if (bid >= 256) {
        // ---- convert path: [b,n,h,c] f32 -> [b,h,n,c] bf16 ----
        int cb = bid - 256;            // 0..2047
        int z = cb >> 10;
        int blk = cb & 1023;
        const float* src = z ? k : q;
        short* dst = z ? kbf : qbf;
        int e0 = (blk * 256 + t) * 16;
        int c = e0 & 63, hh = (e0 >> 6) & 15, n = (e0 >> 10) & 2047, b = e0 >> 21;
        short* dbase = dst + (((size_t)(b * 16 + hh) * 2048) + n) * 64 + c;
#pragma unroll
        for (int i = 0; i < 4; ++i) {
            float4 v = *reinterpret_cast<const float4*>(src + e0 + i * 4);
            short4 o = { f2bf(v.x), f2bf(v.y), f2bf(v.z), f2bf(v.w) };
            *reinterpret_cast<short4*>(dbase + i * 4) = o;
        }
        return;
    }

    // ---- proj path ----
    int z = bid >> 7;
    int d0i = ((bid >> 6) & 1) * 8 + (bid & 7);
    int r0i = (bid >> 3) & 7;
    const float* W    = z ? Wk : Wq;
    const float* bias = z ? bk : bq;
    float* o = out + (z ? OUT_RK : OUT_RQ);
    short* bfo = z ? rkbf : rqbf;
    int r0 = r0i * 64;
    int d0 = d0i * 64;

    {   // LN stats, 4 threads per row
        int rr = t >> 2, p = t & 3;
        const float4* rp = reinterpret_cast<const float4*>(emb + (r0 + rr) * DIM + p * 256);
        float s = 0.f, sq = 0.f;
#pragma unroll
        for (int i = 0; i < 64; ++i) {
            float4 v = rp[i];
            s  += v.x + v.y + v.z + v.w;
            sq += v.x * v.x + v.y * v.y + v.z * v.z + v.w * v.w;
        }
        s += __shfl_xor(s, 1); sq += __shfl_xor(sq, 1);
        s += __shfl_xor(s, 2); sq += __shfl_xor(sq, 2);
        if (p == 0) {
            float mu = s / DIM;
            float var = sq / DIM - mu * mu;
            smu[rr] = mu;
            srs[rr] = rsqrtf(var + 1e-5f);
        }
    }
    __syncthreads();

    int lane = t & 63, w = t >> 6, lr = lane & 15, lg = lane >> 4;
    int srow = t >> 2, seg = (t & 3) * 16;
    float mu = smu[srow], rs = srs[srow];

    f32x4 acc[4] = {};
    for (int c0 = 0; c0 < DIM; c0 += 64) {
        const float4* ep = reinterpret_cast<const float4*>(emb + (size_t)(r0 + srow) * DIM + c0 + seg);
        const float4* wp = reinterpret_cast<const float4*>(W + (size_t)(d0 + srow) * DIM + c0 + seg);
        short4* ad = reinterpret_cast<short4*>(&As[srow * 72 + seg]);
        short4* wd = reinterpret_cast<short4*>(&Bs[srow * 72 + seg]);
#pragma unroll
        for (int i = 0; i < 4; ++i) {
            float4 v = ep[i], wv = wp[i];
            int cb2 = c0 + seg + i * 4;
            float4 sc = *reinterpret_cast<const float4*>(lnsc + cb2);
            float4 bi = *reinterpret_cast<const float4*>(lnbi + cb2);
            short4 a4 = { f2bf((v.x - mu) * rs * sc.x + bi.x),
                          f2bf((v.y - mu) * rs * sc.y + bi.y),
                          f2bf((v.z - mu) * rs * sc.z + bi.z),
                          f2bf((v.w - mu) * rs * sc.w + bi.w) };
            short4 w4 = { f2bf(wv.x), f2bf(wv.y), f2bf(wv.z), f2bf(wv.w) };
            ad[i] = a4;
            wd[i] = w4;
        }
        __syncthreads();
#pragma unroll
        for (int kk = 0; kk < 2; ++kk) {
            bf16x8 a = *reinterpret_cast<const bf16x8*>(&As[(w * 16 + lr) * 72 + kk * 32 + lg * 8]);
#pragma unroll
            for (int cg = 0; cg < 4; ++cg) {
                bf16x8 b = *reinterpret_cast<const bf16x8*>(&Bs[(cg * 16 + lr) * 72 + kk * 32 + lg * 8]);
                acc[cg] = __builtin_amdgcn_mfma_f32_16x16x32_bf16(a, b, acc[cg], 0, 0, 0);
            }
        }
        __syncthreads();
    }
#pragma unroll
    for (int cg = 0; cg < 4; ++cg) {
        int col = d0 + cg * 16 + lr;
        float bv = bias[col];
        int hh = col >> 6, cc = col & 63;
#pragma unroll
        for (int reg = 0; reg < 4; ++reg) {
            int rr = r0 + w * 16 + lg * 4 + reg;
            float val = acc[cg][reg] + bv;
            o[(size_t)rr * DIM + col] = val;
            bfo[((size_t)(hh * 512) + rr) * 64 + cc] = f2bf(val);
        }
    }
}

// cvec: c0/c511 dot tables from bf16 copies. z=0: q . rk[0/511] -> C0Q/C511Q; z=1: k . rq[0/511]
__global__ __launch_bounds__(256) void cvec(const short* __restrict__ qbf,
        const short* __restrict__ kbf, const short* __restrict__ rqbf,
        const short* __restrict__ rkbf, float* __restrict__ ws) {
    int cid = blockIdx.x;           // 0..2047
    int z = cid >> 10;
    int rem = cid & 1023;
    int bh = rem >> 5, rb = rem & 31;
    int t = threadIdx.x;
    int rr = t >> 2, p = t & 3;
    int n = rb * 64 + rr;
    int h = bh & 15;
    const short* X = (z ? kbf : qbf) + ((size_t)bh * 2048 + n) * 64 + p * 16;
    const short* T = (z ? rqbf : rkbf) + (size_t)h * 512 * 64 + p * 16;
    bf16x8 x0 = *reinterpret_cast<const bf16x8*>(X);
    bf16x8 x1 = *reinterpret_cast<const bf16x8*>(X + 8);
    bf16x8 a0 = *reinterpret_cast<const bf16x8*>(T);
    bf16x8 a1 = *reinterpret_cast<const bf16x8*>(T + 8);
    bf16x8 c0 = *reinterpret_cast<const bf16x8*>(T + 511 * 64);
    bf16x8 c1 = *reinterpret_cast<const bf16x8*>(T + 511 * 64 + 8);
    float d0 = 0.f, d1 = 0.f;
#pragma unroll
    for (int e = 0; e < 8; ++e) {
        float xa = bf2f(x0[e]), xb = bf2f(x1[e]);
        d0 += xa * bf2f(a0[e]) + xb * bf2f(a1[e]);
        d1 += xa * bf2f(c0[e]) + xb * bf2f(c1[e]);
    }
    d0 += __shfl_xor(d0, 1); d0 += __shfl_xor(d0, 2);
    d1 += __shfl_xor(d1, 1); d1 += __shfl_xor(d1, 2);
    if (p == 0) {
        int o = bh * S + n;
        if (!z) { ws[WS_C0Q + o] = d0; ws[WS_C511Q + o] = d1; }
        else    { ws[WS_C0K + o] = d0; ws[WS_C511K + o] = d1; }
    }
}

// Unified output kernel. Per panel: nt-major sweep (R8 ordering), flat runs merged into
// 64x512 superblocks (2KB-contiguous row spans). 373 blocks/panel, 64 panels = 23872.
__global__ __launch_bounds__(256) void outk(const short* __restrict__ qbf,
        const short* __restrict__ kbf, const short* __restrict__ rqbf,
        const short* __restrict__ rkbf, const float* __restrict__ ws,
        float* __restrict__ out) {
    __shared__ short Yt[128 * 68];   // [g][m] (band path only)

    int bid = blockIdx.x;
    int wid = (bid & 7) * 2984 + (bid >> 3);   // 23872 = 8*2984, bijective
    int panel = wid / 373, o = wid % 373;
    int PK = panel >> 5, bh = panel & 31, h = bh & 15;
    int t = threadIdx.x;
    float* obase = out + (PK ? OUT_PK : OUT_QP) + (size_t)bh * S * S;

    // locate within panel: for each nt, [nL left-superblocks][nB band][nR right-superblocks]
    int nt = 0, rem = o, nL = 0, nB = 0, jlo = 0;
    for (; nt < 32; ++nt) {
        jlo = nt > 8 ? nt - 8 : 0;
        nL = (jlo + 7) >> 3;          // ceil(jlo*64/512)
        nB = nt - jlo + 1;
        int nR = (38 - nt) >> 3;      // ceil((2048-(nt+1)*64)/512)
        int tot = nL + nB + nR;
        if (rem < tot) break;
        rem -= tot;
    }
    int n0 = nt * 64;

    if (rem < nL || rem >= nL + nB) {
        // ---- flat superblock: 64 rows x W cols (W<=512) ----
        int left, j0, W;
        if (rem < nL) { left = 1; j0 = rem * 512; W = jlo * 64 - j0; }
        else          { left = 0; int rr = rem - nL - nB; j0 = (nt + 1) * 64 + rr * 512; W = 2048 - j0; }
        if (W > 512) W = 512;
        const float* cv = ws + (PK ? (left ? WS_C0K : WS_C511K)
                                   : (left ? WS_C0Q : WS_C511Q)) + bh * S;
        int w2 = t >> 7;                 // 2 row-groups of 32 rows
        int c = (t & 127) * 4;           // 128 col-threads x 4 floats = 512 cols
        int active = c < W;
        if (PK) {
            f32x4 cvv = {0.f, 0.f, 0.f, 0.f};
            if (active) cvv = *reinterpret_cast<const f32x4*>(cv + j0 + c);
#pragma unroll
            for (int i = 0; i < 32; ++i) {
                int n = n0 + w2 * 32 + i;
                if (active)
                    __builtin_nontemporal_store(cvv,
                        reinterpret_cast<f32x4*>(obase + (size_t)n * S + j0 + c));
            }
        } else {
#pragma unroll
            for (int i = 0; i < 32; ++i) {
                int n = n0 + w2 * 32 + i;
                float vs = cv[n];
                f32x4 v = { vs, vs, vs, vs };
                if (active)
                    __builtin_nontemporal_store(v,
                        reinterpret_cast<f32x4*>(obase + (size_t)n * S + j0 + c));
            }
        }
        return;
    }

    // ---- band tile ----
    int jt = jlo + (rem - nL);
    int j0 = jt * 64;
    int rlo = 511 + j0 - (n0 + 63); rlo = rlo < 0 ? 0 : rlo;

    const short* xb = (PK ? kbf : qbf) + ((size_t)bh * 2048 + (PK ? j0 : n0)) * 64;
    const short* tbase = (PK ? rqbf : rkbf) + (size_t)h * 512 * 64;

    int lane = t & 63, w = t >> 6, lr = lane & 15, lg = lane >> 4;
    // Same (lr, lg) convention for A and B => HW k-permutation cancels (verified R2-R13).
    const short* arow = xb + (w * 16 + lr) * 64 + lg * 8;
    bf16x8 a0 = *reinterpret_cast<const bf16x8*>(arow);
    bf16x8 a1 = *reinterpret_cast<const bf16x8*>(arow + 32);

    bf16x8 b0s[8], b1s[8];
#pragma unroll
    for (int s = 0; s < 8; ++s) {
        int trow = rlo + s * 16 + lr;
        trow = trow > 511 ? 511 : trow;   // in-bounds; g>=nT never gathered
        const short* brow = tbase + trow * 64 + lg * 8;
        b0s[s] = *reinterpret_cast<const bf16x8*>(brow);
        b1s[s] = *reinterpret_cast<const bf16x8*>(brow + 32);
    }
#pragma unroll
    for (int s = 0; s < 8; ++s) {
        f32x4 acc = {0.f, 0.f, 0.f, 0.f};
        acc = __builtin_amdgcn_mfma_f32_16x16x32_bf16(a0, b0s[s], acc, 0, 0, 0);
        acc = __builtin_amdgcn_mfma_f32_16x16x32_bf16(a1, b1s[s], acc, 0, 0, 0);
        // lane's acc[reg] = Y[m = w*16+lg*4+reg, g = s*16+lr] -> ds_write_b64 at Yt[g][m0]
        short4 pk4 = { f2bf(acc[0]), f2bf(acc[1]), f2bf(acc[2]), f2bf(acc[3]) };
        *reinterpret_cast<short4*>(&Yt[(s * 16 + lr) * 68 + w * 16 + lg * 4]) = pk4;
    }
    __syncthreads();

    int tx = t & 15, ty = t >> 4;
#pragma unroll
    for (int i = 0; i < 4; ++i) {
        int rowi = ty + i * 16;
        int n = n0 + rowi;
        float vv[4];
#pragma unroll
        for (int jj = 0; jj < 4; ++jj) {
            int j = j0 + tx * 4 + jj;
            int rel = 511 + j - n;
            rel = rel < 0 ? 0 : (rel > 511 ? 511 : rel);
            int g = rel - rlo;
            int m = PK ? (tx * 4 + jj) : rowi;
            vv[jj] = bf2f(Yt[g * 68 + m]);
        }
        f32x4 v = { vv[0], vv[1], vv[2], vv[3] };
        __builtin_nontemporal_store(v,
            reinterpret_cast<f32x4*>(obase + (size_t)n * S + j0 + tx * 4));
    }
}

extern "C" void kernel_launch(void* const* d_in, const int* in_sizes, int n_in,
                              void* d_out, int out_size, void* d_ws, size_t ws_size,
                              hipStream_t stream) {
    const float* q    = (const float*)d_in[0];
    const float* k    = (const float*)d_in[1];
    const float* emb  = (const float*)d_in[2];
    const float* lnsc = (const float*)d_in[3];
    const float* lnbi = (const float*)d_in[4];
    const float* Wq   = (const float*)d_in[5];
    const float* bq   = (const float*)d_in[6];
    const float* Wk   = (const float*)d_in[7];
    const float* bk   = (const float*)d_in[8];
    float* out = (float*)d_out;
    float* ws  = (float*)d_ws;

    short* qbf  = (short*)(ws + WS_BF_BASE);
    short* kbf  = qbf + (size_t)4194304;
    short* rqbf = kbf + (size_t)4194304;
    short* rkbf = rqbf + (size_t)524288;

    prep1<<<dim3(2304), dim3(256), 0, stream>>>(emb, lnsc, lnbi, Wq, bq, Wk, bk,
                                                q, k, out, rqbf, rkbf, qbf, kbf);
    cvec<<<dim3(2048), dim3(256), 0, stream>>>(qbf, kbf, rqbf, rkbf, ws);
    outk<<<dim3(23872), dim3(256), 0, stream>>>(qbf, kbf, rqbf, rkbf, ws, out);
}